// Round 1
// baseline (3685.129 us; speedup 1.0000x reference)
//
#include <hip/hip_runtime.h>
#include <math.h>
#include <string.h>

#define CK 1024
#define BATCH 8

struct F16x8 { float m[16][8]; };

// ============================ host-side filter construction ============================
// Port of _legendre_filters(8) in double precision. Deterministic, ~microseconds, pure CPU.

static void compose_poly(const double* a, int deg, double alpha, double beta, double* out16)
{
    // coefficients (ascending) of sum_j a[j] * (alpha*x + beta)^j, via polynomial Horner
    double r[20]; for (int i = 0; i < 20; ++i) r[i] = 0.0;
    int rd = -1;
    for (int j = deg; j >= 0; --j) {
        double nr[20]; for (int i = 0; i < 20; ++i) nr[i] = 0.0;
        for (int i = 0; i <= rd; ++i) { nr[i] += beta * r[i]; nr[i + 1] += alpha * r[i]; }
        nr[0] += a[j];
        rd = (rd < 0) ? 0 : (rd + 1);
        for (int i = 0; i < 20; ++i) r[i] = nr[i];
    }
    for (int i = 0; i < 16; ++i) out16[i] = r[i];
}

static double inner_prod(const double* a, int la, const double* b, int lb, int half)
{
    double prod[40]; for (int i = 0; i < 40; ++i) prod[i] = 0.0;
    for (int i = 0; i < la; ++i)
        for (int j = 0; j < lb; ++j) prod[i + j] += a[i] * b[j];
    int lp = la + lb - 1;
    double s = 0.0;
    for (int r = 0; r < lp; ++r) {
        double p = prod[r];
        if (fabs(p) < 1e-8) p = 0.0;
        double w = pow(0.5, (double)(r + 1));
        if (!half) w = 1.0 - w;
        s += p / ((double)(r + 1)) * w;
    }
    return s;
}

static double polyval8(const double* c, double x)
{
    double r = 0.0;
    for (int i = 7; i >= 0; --i) r = r * x + c[i];
    return r;
}

static void host_filters(F16x8* ecs, F16x8* ecd, F16x8* rce, F16x8* rco)
{
    // Legendre P_0..P_7 monomial coefficients (ascending)
    static const double Lg[8][8] = {
        {1, 0, 0, 0, 0, 0, 0, 0},
        {0, 1, 0, 0, 0, 0, 0, 0},
        {-0.5, 0, 1.5, 0, 0, 0, 0, 0},
        {0, -1.5, 0, 2.5, 0, 0, 0, 0},
        {0.375, 0, -3.75, 0, 4.375, 0, 0, 0},
        {0, 1.875, 0, -8.75, 0, 7.875, 0, 0},
        {-0.3125, 0, 6.5625, 0, -19.6875, 0, 14.4375, 0},
        {0, -2.1875, 0, 19.6875, 0, -43.3125, 0, 26.8125}
    };
    double phi[8][16], phi2[8][16], psi1[8][16], psi2[8][16];
    for (int i = 0; i < 8; ++i)
        for (int j = 0; j < 16; ++j) { phi[i][j] = 0; phi2[i][j] = 0; psi1[i][j] = 0; psi2[i][j] = 0; }

    for (int ki = 0; ki < 8; ++ki) {
        double c1[16], c2[16];
        compose_poly(Lg[ki], ki, 2.0, -1.0, c1);
        compose_poly(Lg[ki], ki, 4.0, -1.0, c2);
        double s = sqrt(2.0 * ki + 1.0);
        for (int j = 0; j <= ki; ++j) {
            phi[ki][j]  = s * c1[j];
            phi2[ki][j] = 1.4142135623730951 * s * c2[j];
        }
    }

    for (int ki = 0; ki < 8; ++ki) {
        for (int j = 0; j < 8; ++j) psi1[ki][j] = phi2[ki][j];
        // psi2 row starts at zero
        for (int i = 0; i < 8; ++i) {
            double p = inner_prod(phi2[ki], ki + 1, phi[i], i + 1, 1);
            for (int j = 0; j < 8; ++j) { psi1[ki][j] -= p * phi[i][j]; psi2[ki][j] -= p * phi[i][j]; }
        }
        for (int j = 0; j < ki; ++j) {
            double p = inner_prod(phi2[ki], ki + 1, psi1[j], 8, 1);
            for (int q = 0; q < 8; ++q) { psi1[ki][q] -= p * psi1[j][q]; psi2[ki][q] -= p * psi2[j][q]; }
        }
        double n1 = inner_prod(psi1[ki], 8, psi1[ki], 8, 1);
        double n2 = inner_prod(psi2[ki], 8, psi2[ki], 8, 0);
        double nrm = sqrt(n1 + n2);
        for (int q = 0; q < 8; ++q) {
            psi1[ki][q] /= nrm; psi2[ki][q] /= nrm;
            if (fabs(psi1[ki][q]) < 1e-8) psi1[ki][q] = 0.0;
            if (fabs(psi2[ki][q]) < 1e-8) psi2[ki][q] = 0.0;
        }
    }

    static const double gx[8] = {
        -0.96028985649753623168, -0.79666647741362673959, -0.52553240991632898582, -0.18343464249564980494,
         0.18343464249564980494,  0.52553240991632898582,  0.79666647741362673959,  0.96028985649753623168 };
    static const double gw[8] = {
         0.10122853629037625915,  0.22238103445337447054,  0.31370664587788728734,  0.36268378337836198297,
         0.36268378337836198297,  0.31370664587788728734,  0.22238103445337447054,  0.10122853629037625915 };

    double H0[8][8], H1[8][8], G0[8][8], G1[8][8];
    const double s2 = 0.70710678118654752440;
    for (int ki = 0; ki < 8; ++ki) {
        for (int kpi = 0; kpi < 8; ++kpi) {
            double h0 = 0, h1 = 0, g0 = 0, g1 = 0;
            for (int mq = 0; mq < 8; ++mq) {
                double xm = (gx[mq] + 1.0) * 0.5;
                double wm = gw[mq] * 0.5;
                double pk = polyval8(phi[kpi], xm);
                h0 += wm * polyval8(phi[ki],  xm * 0.5) * pk;
                g0 += wm * polyval8(psi1[ki], xm * 0.5) * pk;          // arg <= 0.5 -> psi1
                h1 += wm * polyval8(phi[ki],  (xm + 1.0) * 0.5) * pk;
                g1 += wm * polyval8(psi2[ki], (xm + 1.0) * 0.5) * pk;  // arg > 0.5 -> psi2
            }
            h0 *= s2; h1 *= s2; g0 *= s2; g1 *= s2;
            H0[ki][kpi] = (fabs(h0) < 1e-8) ? 0.0 : h0;
            H1[ki][kpi] = (fabs(h1) < 1e-8) ? 0.0 : h1;
            G0[ki][kpi] = (fabs(g0) < 1e-8) ? 0.0 : g0;
            G1[ki][kpi] = (fabs(g1) < 1e-8) ? 0.0 : g1;
        }
    }

    for (int r = 0; r < 8; ++r) {
        for (int c = 0; c < 8; ++c) {
            ecs->m[r][c]     = (float)H0[c][r];   // EC_S = [H0^T ; H1^T]
            ecs->m[r + 8][c] = (float)H1[c][r];
            ecd->m[r][c]     = (float)G0[c][r];   // EC_D = [G0^T ; G1^T]
            ecd->m[r + 8][c] = (float)G1[c][r];
            rce->m[r][c]     = (float)H0[r][c];   // RC_E = [H0 ; G0]
            rce->m[r + 8][c] = (float)G0[r][c];
            rco->m[r][c]     = (float)H1[r][c];   // RC_O = [H1 ; G1]
            rco->m[r + 8][c] = (float)G1[r][c];
        }
    }
}

// ============================ device kernels ============================

// C(M,N) = A(M,K) * B(N,K)^T + bias(N). 128x128 tile, BK=8, 256 threads, 8x8 per thread.
__global__ __launch_bounds__(256) void gemm_nt(
    const float* __restrict__ A, const float* __restrict__ B,
    const float* __restrict__ bias, float* __restrict__ C,
    int M, int N, int K)
{
    __shared__ __align__(16) float As[8][128];
    __shared__ __align__(16) float Bs[8][128];
    const int tid = threadIdx.x;
    const int bm = blockIdx.y * 128, bn = blockIdx.x * 128;
    const int lr = tid >> 1, lk = (tid & 1) * 4;
    const int tm = (tid >> 4) * 8, tn = (tid & 15) * 8;
    const float* Ap = A + (size_t)(bm + lr) * K + lk;
    const float* Bp = B + (size_t)(bn + lr) * K + lk;
    float acc[8][8];
#pragma unroll
    for (int i = 0; i < 8; ++i)
#pragma unroll
        for (int j = 0; j < 8; ++j) acc[i][j] = 0.f;

    for (int k0 = 0; k0 < K; k0 += 8) {
        float4 a4 = *(const float4*)(Ap + k0);
        float4 b4 = *(const float4*)(Bp + k0);
        __syncthreads();
        As[lk + 0][lr] = a4.x; As[lk + 1][lr] = a4.y; As[lk + 2][lr] = a4.z; As[lk + 3][lr] = a4.w;
        Bs[lk + 0][lr] = b4.x; Bs[lk + 1][lr] = b4.y; Bs[lk + 2][lr] = b4.z; Bs[lk + 3][lr] = b4.w;
        __syncthreads();
#pragma unroll
        for (int kk = 0; kk < 8; ++kk) {
            alignas(16) float ar[8], br[8];
            *(float4*)&ar[0] = *(const float4*)&As[kk][tm];
            *(float4*)&ar[4] = *(const float4*)&As[kk][tm + 4];
            *(float4*)&br[0] = *(const float4*)&Bs[kk][tn];
            *(float4*)&br[4] = *(const float4*)&Bs[kk][tn + 4];
#pragma unroll
            for (int i = 0; i < 8; ++i)
#pragma unroll
                for (int j = 0; j < 8; ++j) acc[i][j] = fmaf(ar[i], br[j], acc[i][j]);
        }
    }
    float bb[8];
#pragma unroll
    for (int j = 0; j < 8; ++j) bb[j] = bias[bn + tn + j];
#pragma unroll
    for (int i = 0; i < 8; ++i) {
        alignas(16) float cv[8];
#pragma unroll
        for (int j = 0; j < 8; ++j) cv[j] = acc[i][j] + bb[j];
        size_t off = (size_t)(bm + tm + i) * N + bn + tn;
        *(float4*)&C[off]     = *(float4*)&cv[0];
        *(float4*)&C[off + 4] = *(float4*)&cv[4];
    }
}

// wavelet decomposition step: x(B,2Nh,1024) -> d_all,s_all rows [b*1023 + out_off + t]
__global__ __launch_bounds__(256) void decomp_k(
    const float* __restrict__ xin, float* __restrict__ d_all, float* __restrict__ s_all,
    F16x8 ecd, F16x8 ecs, int Nh, int out_off, int in_bstride, int in_off)
{
    int idx = blockIdx.x * 256 + threadIdx.x;
    int total = BATCH * Nh * 128;
    if (idx >= total) return;
    int ch = idx & 127;
    int t  = (idx >> 7) % Nh;
    int b  = idx / (128 * Nh);
    const float* x0 = xin + ((size_t)b * in_bstride + in_off + 2 * t) * CK + ch * 8;
    alignas(16) float xa[16];
    *(float4*)&xa[0]  = *(const float4*)(x0);
    *(float4*)&xa[4]  = *(const float4*)(x0 + 4);
    *(float4*)&xa[8]  = *(const float4*)(x0 + CK);
    *(float4*)&xa[12] = *(const float4*)(x0 + CK + 4);
    alignas(16) float dd[8], ss[8];
#pragma unroll
    for (int q = 0; q < 8; ++q) { dd[q] = 0.f; ss[q] = 0.f; }
#pragma unroll
    for (int j = 0; j < 16; ++j) {
        float v = xa[j];
#pragma unroll
        for (int q = 0; q < 8; ++q) {
            dd[q] = fmaf(v, ecd.m[j][q], dd[q]);
            ss[q] = fmaf(v, ecs.m[j][q], ss[q]);
        }
    }
    size_t ob = ((size_t)b * 1023 + out_off + t) * CK + ch * 8;
    *(float4*)&d_all[ob]     = *(float4*)&dd[0];
    *(float4*)&d_all[ob + 4] = *(float4*)&dd[4];
    *(float4*)&s_all[ob]     = *(float4*)&ss[0];
    *(float4*)&s_all[ob + 4] = *(float4*)&ss[4];
}

// forward 16-mode DFT along time. X[(lev*8+b)*16+m][i][{re,im}]
template<int LN>
__global__ __launch_bounds__(256) void dft_k(
    const float* __restrict__ d_all, const float* __restrict__ s_all,
    float* __restrict__ Xd, float* __restrict__ Xs, int lev0)
{
    const int lev = lev0 + (int)blockIdx.z / 2;
    const int src = (int)blockIdx.z & 1;
    const int Nh  = 512 >> lev;
    const int off = 1024 - (1024 >> lev);
    const int i   = blockIdx.x * 256 + threadIdx.x;
    const int b   = blockIdx.y;
    const float* inp = (src == 0 ? d_all : s_all) + ((size_t)b * 1023 + off) * CK + i;
    float* Xout = (src == 0 ? Xd : Xs);
    float accr[LN], acci[LN];
#pragma unroll
    for (int m = 0; m < LN; ++m) { accr[m] = 0.f; acci[m] = 0.f; }
    __shared__ float2 tw[128][LN];
    for (int t0 = 0; t0 < Nh; t0 += 128) {
        int tc = Nh - t0; if (tc > 128) tc = 128;
        __syncthreads();
        for (int e = threadIdx.x; e < tc * LN; e += 256) {
            int tt = e / LN, m = e - tt * LN;
            int r = (int)(((long long)(t0 + tt) * m) % Nh);
            float ang = -6.283185307179586f * (float)r / (float)Nh;
            float sv, cv;
            sincosf(ang, &sv, &cv);
            tw[tt][m] = make_float2(cv, sv);
        }
        __syncthreads();
        for (int tt = 0; tt < tc; ++tt) {
            float v = inp[(size_t)(t0 + tt) * CK];
#pragma unroll
            for (int m = 0; m < LN; ++m) {
                float2 w = tw[tt][m];
                accr[m] = fmaf(v, w.x, accr[m]);
                acci[m] = fmaf(v, w.y, acci[m]);
            }
        }
    }
#pragma unroll
    for (int m = 0; m < LN; ++m) {
        size_t row = (size_t)((lev * 8 + b) * 16 + m);
        *(float2*)(Xout + row * 2048 + 2 * i) = make_float2(accr[m], acci[m]);
    }
}

// mode mixing: Uhd = wA*Xd + wB*Xs ; Uhs = wC*Xd  (complex, per mode, summed over i=0..1023)
// weights in native (i,o,m) layout; float4 across contiguous m. XCD-aware block swizzle.
__global__ __launch_bounds__(256) void modemix_k(
    const float* __restrict__ wAre, const float* __restrict__ wAim,
    const float* __restrict__ wBre, const float* __restrict__ wBim,
    const float* __restrict__ wCre, const float* __restrict__ wCim,
    const float* __restrict__ Xd, const float* __restrict__ Xs,
    float* __restrict__ Uhd, float* __restrict__ Uhs)
{
    // 640 blocks = 16 o-tiles x 10 levels x 4 b-pairs, swizzled so the 40 blocks
    // sharing one o-tile's weight slice land on 2 XCDs (assumes XCD = blockIdx % 8).
    int bid = (int)blockIdx.x;
    int xcd = bid & 7, slot = bid >> 3;       // slot 0..79
    int grp_on = slot / 20, member = slot - grp_on * 20;
    int group = grp_on * 8 + xcd;             // 0..31
    int ot = group >> 1, hv = group & 1;
    int pairidx = hv * 20 + member;           // 0..39
    int lev = pairidx >> 2, bpair = pairidx & 3;

    const int Nh = 512 >> lev;
    const int ln = min(16, (Nh >> 1) + 1);
    const int mg = (int)threadIdx.x >> 6;
    if (mg * 4 >= ln) return;                 // wave-uniform early exit
    const int o  = ot * 64 + ((int)threadIdx.x & 63);
    const int m0 = mg * 4;
    const int b0 = bpair * 2;

    float aUr[4][2], aUi[4][2], aSr[4][2], aSi[4][2];
#pragma unroll
    for (int mi = 0; mi < 4; ++mi)
#pragma unroll
        for (int bi = 0; bi < 2; ++bi) { aUr[mi][bi] = 0.f; aUi[mi][bi] = 0.f; aSr[mi][bi] = 0.f; aSi[mi][bi] = 0.f; }

    const float* xdp[4][2]; const float* xsp[4][2];
#pragma unroll
    for (int mi = 0; mi < 4; ++mi)
#pragma unroll
        for (int bi = 0; bi < 2; ++bi) {
            size_t row = (size_t)((lev * 8 + b0 + bi) * 16 + m0 + mi);
            xdp[mi][bi] = Xd + row * 2048;
            xsp[mi][bi] = Xs + row * 2048;
        }

    const size_t wo0 = (size_t)o * 16 + m0;
    for (int i = 0; i < 1024; ++i) {
        size_t wo = wo0 + (size_t)i * 16384;
        float4 war = *(const float4*)(wAre + wo);
        float4 wai = *(const float4*)(wAim + wo);
        float4 wbr = *(const float4*)(wBre + wo);
        float4 wbi = *(const float4*)(wBim + wo);
        float4 wcr = *(const float4*)(wCre + wo);
        float4 wci = *(const float4*)(wCim + wo);
        const float warr[4] = {war.x, war.y, war.z, war.w};
        const float wair[4] = {wai.x, wai.y, wai.z, wai.w};
        const float wbrr[4] = {wbr.x, wbr.y, wbr.z, wbr.w};
        const float wbir[4] = {wbi.x, wbi.y, wbi.z, wbi.w};
        const float wcrr[4] = {wcr.x, wcr.y, wcr.z, wcr.w};
        const float wcir[4] = {wci.x, wci.y, wci.z, wci.w};
#pragma unroll
        for (int mi = 0; mi < 4; ++mi) {
            const float ar_ = warr[mi], ai_ = wair[mi];
            const float br_ = wbrr[mi], bi_ = wbir[mi];
            const float cr_ = wcrr[mi], ci_ = wcir[mi];
#pragma unroll
            for (int bi = 0; bi < 2; ++bi) {
                float2 xd2 = *(const float2*)(xdp[mi][bi] + 2 * i);
                float2 xs2 = *(const float2*)(xsp[mi][bi] + 2 * i);
                aUr[mi][bi] += xd2.x * ar_ - xd2.y * ai_ + xs2.x * br_ - xs2.y * bi_;
                aUi[mi][bi] += xd2.x * ai_ + xd2.y * ar_ + xs2.x * bi_ + xs2.y * br_;
                aSr[mi][bi] += xd2.x * cr_ - xd2.y * ci_;
                aSi[mi][bi] += xd2.x * ci_ + xd2.y * cr_;
            }
        }
    }
#pragma unroll
    for (int mi = 0; mi < 4; ++mi)
#pragma unroll
        for (int bi = 0; bi < 2; ++bi) {
            size_t row = (size_t)((lev * 8 + b0 + bi) * 16 + m0 + mi);
            *(float2*)(Uhd + row * 2048 + 2 * o) = make_float2(aUr[mi][bi], aUi[mi][bi]);
            *(float2*)(Uhs + row * 2048 + 2 * o) = make_float2(aSr[mi][bi], aSi[mi][bi]);
        }
}

// inverse truncated DFT (numpy irfft semantics: interior modes x2, DC/Nyquist real-only)
template<int LN>
__global__ __launch_bounds__(256) void idft_k(
    const float* __restrict__ Uhd, const float* __restrict__ Uhs,
    float* __restrict__ Ud_all, float* __restrict__ Us_all, int lev0)
{
    const int lev = lev0 + (int)blockIdx.z / 8;
    const int chunk = (int)blockIdx.z & 7;
    const int Nh  = 512 >> lev;
    const int off = 1024 - (1024 >> lev);
    const int nch = (Nh + 7) >> 3;
    const int t0 = chunk * nch;
    if (t0 >= Nh) return;
    int t1 = t0 + nch; if (t1 > Nh) t1 = Nh;
    const int o = blockIdx.x * 256 + threadIdx.x;
    const int b = blockIdx.y;
    const float invN = 1.0f / (float)Nh;

    float udr[LN], udi[LN], usr[LN], usi[LN], rc[LN], rs[LN], stc[LN], sts[LN];
#pragma unroll
    for (int m = 0; m < LN; ++m) {
        size_t row = (size_t)((lev * 8 + b) * 16 + m);
        float2 vd = *(const float2*)(Uhd + row * 2048 + 2 * o);
        float2 vs = *(const float2*)(Uhs + row * 2048 + 2 * o);
        bool nyq = (2 * m == Nh);
        float cm = (m == 0 || nyq) ? 1.f : 2.f;
        float sc = cm * invN;
        udr[m] = vd.x * sc; usr[m] = vs.x * sc;
        udi[m] = (m == 0 || nyq) ? 0.f : vd.y * sc;
        usi[m] = (m == 0 || nyq) ? 0.f : vs.y * sc;
        int r = (int)(((long long)m * t0) % Nh);
        float a0 = 6.283185307179586f * (float)r / (float)Nh;
        sincosf(a0, &rs[m], &rc[m]);
        float a1 = 6.283185307179586f * (float)m / (float)Nh;
        sincosf(a1, &sts[m], &stc[m]);
    }
    for (int t = t0; t < t1; ++t) {
        float od = 0.f, os = 0.f;
#pragma unroll
        for (int m = 0; m < LN; ++m) {
            od += udr[m] * rc[m] - udi[m] * rs[m];
            os += usr[m] * rc[m] - usi[m] * rs[m];
            float nc = rc[m] * stc[m] - rs[m] * sts[m];
            float ns = rs[m] * stc[m] + rc[m] * sts[m];
            rc[m] = nc; rs[m] = ns;
        }
        size_t ob = ((size_t)b * 1023 + off + t) * CK + o;
        Ud_all[ob] = od; Us_all[ob] = os;
    }
}

// coarsest-scale linear map: x(B,1,1024) -> T0_w @ (per 8-vector) + T0_b
__global__ __launch_bounds__(256) void t0_k(
    const float* __restrict__ s_all, const float* __restrict__ T0_w,
    const float* __restrict__ T0_b, float* __restrict__ xout)
{
    int idx = blockIdx.x * 256 + threadIdx.x;   // 8192 total
    int o = idx & 1023, b = idx >> 10;
    int ki = o & 7, ch = o >> 3;
    const float* src = s_all + ((size_t)b * 1023 + 1022) * CK + ch * 8;
    float acc = T0_b[ki];
#pragma unroll
    for (int kj = 0; kj < 8; ++kj) acc += src[kj] * T0_w[ki * 8 + kj];
    xout[(size_t)b * 1024 + o] = acc;
}

// reconstruction step: x += Us ; xc=[x,Ud] ; even/odd filters; interleave to 2n rows
__global__ __launch_bounds__(256) void recon_k(
    const float* __restrict__ xin, const float* __restrict__ Ud_all, const float* __restrict__ Us_all,
    float* __restrict__ xout, F16x8 rce, F16x8 rco, int n, int lev_off)
{
    int idx = blockIdx.x * 256 + threadIdx.x;
    int total = BATCH * n * 128;
    if (idx >= total) return;
    int ch = idx & 127;
    int t  = (idx >> 7) % n;
    int b  = idx / (128 * n);
    size_t ib = ((size_t)b * n + t) * CK + ch * 8;
    size_t ub = ((size_t)b * 1023 + lev_off + t) * CK + ch * 8;
    alignas(16) float xc[16];
    float4 xv0 = *(const float4*)(xin + ib);
    float4 xv1 = *(const float4*)(xin + ib + 4);
    float4 us0 = *(const float4*)(Us_all + ub);
    float4 us1 = *(const float4*)(Us_all + ub + 4);
    xc[0] = xv0.x + us0.x; xc[1] = xv0.y + us0.y; xc[2] = xv0.z + us0.z; xc[3] = xv0.w + us0.w;
    xc[4] = xv1.x + us1.x; xc[5] = xv1.y + us1.y; xc[6] = xv1.z + us1.z; xc[7] = xv1.w + us1.w;
    float4 ud0 = *(const float4*)(Ud_all + ub);
    float4 ud1 = *(const float4*)(Ud_all + ub + 4);
    xc[8] = ud0.x; xc[9] = ud0.y; xc[10] = ud0.z; xc[11] = ud0.w;
    xc[12] = ud1.x; xc[13] = ud1.y; xc[14] = ud1.z; xc[15] = ud1.w;
    alignas(16) float ev[8], ov[8];
#pragma unroll
    for (int q = 0; q < 8; ++q) { ev[q] = 0.f; ov[q] = 0.f; }
#pragma unroll
    for (int j = 0; j < 16; ++j) {
        float v = xc[j];
#pragma unroll
        for (int q = 0; q < 8; ++q) {
            ev[q] = fmaf(v, rce.m[j][q], ev[q]);
            ov[q] = fmaf(v, rco.m[j][q], ov[q]);
        }
    }
    size_t ob = ((size_t)b * 2 * n + 2 * t) * CK + ch * 8;
    *(float4*)&xout[ob]          = *(float4*)&ev[0];
    *(float4*)&xout[ob + 4]      = *(float4*)&ev[4];
    *(float4*)&xout[ob + CK]     = *(float4*)&ov[0];
    *(float4*)&xout[ob + CK + 4] = *(float4*)&ov[4];
}

// ============================ launch ============================

extern "C" void kernel_launch(void* const* d_in, const int* in_sizes, int n_in,
                              void* d_out, int out_size, void* d_ws, size_t ws_size,
                              hipStream_t stream)
{
    (void)in_sizes; (void)n_in; (void)out_size; (void)ws_size;
    const float* values = (const float*)d_in[2];
    const float* Lk0_w  = (const float*)d_in[3];
    const float* Lk0_b  = (const float*)d_in[4];
    const float* Lk1_w  = (const float*)d_in[5];
    const float* Lk1_b  = (const float*)d_in[6];
    const float* T0_w   = (const float*)d_in[7];
    const float* T0_b   = (const float*)d_in[8];
    const float* wAre   = (const float*)d_in[9];
    const float* wAim   = (const float*)d_in[10];
    const float* wBre   = (const float*)d_in[11];
    const float* wBim   = (const float*)d_in[12];
    const float* wCre   = (const float*)d_in[13];
    const float* wCim   = (const float*)d_in[14];
    float* out = (float*)d_out;
    float* ws  = (float*)d_ws;

    // workspace layout (floats); total 51,347,456 floats = 196 MiB
    float* V0     = ws;                      // 8388608  (Lk0 out / recon ping A)
    float* xrB    = V0 + 8388608;            // 4194304  (recon ping B, max 512 rows)
    float* d_all  = xrB + 4194304;           // 8380416
    float* s_all  = d_all + 8380416;         // 8380416
    float* Ud_all = s_all + 8380416;         // 8380416
    float* Us_all = Ud_all + 8380416;        // 8380416
    float* Xd     = Us_all + 8380416;        // 2621440
    float* Xs     = Xd + 2621440;            // 2621440
    float* Uhd    = d_all;                   // overlay: d_all dead after DFT phase
    float* Uhs    = d_all + 2621440;

    F16x8 ecs, ecd, rce, rco;
    host_filters(&ecs, &ecd, &rce, &rco);

    // 1) V0 = values @ Lk0_w^T + Lk0_b   (8192 x 1024, K=512)
    gemm_nt<<<dim3(8, 64), 256, 0, stream>>>(values, Lk0_w, Lk0_b, V0, 8192, 1024, 512);

    // 2) decomposition cascade (10 levels)
    for (int lev = 0; lev < 10; ++lev) {
        int Nh = 512 >> lev;
        int out_off = 1024 - (1024 >> lev);
        const float* xin; int in_bs, in_off;
        if (lev == 0) { xin = V0; in_bs = 1024; in_off = 0; }
        else { xin = s_all; in_bs = 1023; in_off = 1024 - (1024 >> (lev - 1)); }
        int blocks = (BATCH * Nh * 128 + 255) / 256;
        decomp_k<<<blocks, 256, 0, stream>>>(xin, d_all, s_all, ecd, ecs, Nh, out_off, in_bs, in_off);
    }

    // 3) forward truncated DFTs (levels 0-4 grouped; deep levels tiny)
    dft_k<16><<<dim3(4, 8, 10), 256, 0, stream>>>(d_all, s_all, Xd, Xs, 0);
    dft_k<9> <<<dim3(4, 8, 2), 256, 0, stream>>>(d_all, s_all, Xd, Xs, 5);
    dft_k<5> <<<dim3(4, 8, 2), 256, 0, stream>>>(d_all, s_all, Xd, Xs, 6);
    dft_k<3> <<<dim3(4, 8, 2), 256, 0, stream>>>(d_all, s_all, Xd, Xs, 7);
    dft_k<2> <<<dim3(4, 8, 2), 256, 0, stream>>>(d_all, s_all, Xd, Xs, 8);
    dft_k<1> <<<dim3(4, 8, 2), 256, 0, stream>>>(d_all, s_all, Xd, Xs, 9);

    // 4) coarsest-scale T0 map into recon start buffer (V0, compact b-rows)
    t0_k<<<32, 256, 0, stream>>>(s_all, T0_w, T0_b, V0);

    // 5) mode mixing (overwrites d_all region with Uhat; d_all fully consumed above)
    modemix_k<<<640, 256, 0, stream>>>(wAre, wAim, wBre, wBim, wCre, wCim, Xd, Xs, Uhd, Uhs);

    // 6) inverse truncated DFTs -> Ud_all / Us_all
    idft_k<16><<<dim3(4, 8, 40), 256, 0, stream>>>(Uhd, Uhs, Ud_all, Us_all, 0);
    idft_k<9> <<<dim3(4, 8, 8), 256, 0, stream>>>(Uhd, Uhs, Ud_all, Us_all, 5);
    idft_k<5> <<<dim3(4, 8, 8), 256, 0, stream>>>(Uhd, Uhs, Ud_all, Us_all, 6);
    idft_k<3> <<<dim3(4, 8, 8), 256, 0, stream>>>(Uhd, Uhs, Ud_all, Us_all, 7);
    idft_k<2> <<<dim3(4, 8, 8), 256, 0, stream>>>(Uhd, Uhs, Ud_all, Us_all, 8);
    idft_k<1> <<<dim3(4, 8, 8), 256, 0, stream>>>(Uhd, Uhs, Ud_all, Us_all, 9);

    // 7) reconstruction cascade (ping-pong V0 <-> xrB; ends in V0)
    float* cur = V0; float* nxt = xrB;
    for (int lv = 9; lv >= 0; --lv) {
        int n = 512 >> lv;
        int off = 1024 - (1024 >> lv);
        int blocks = (BATCH * n * 128 + 255) / 256;
        recon_k<<<blocks, 256, 0, stream>>>(cur, Ud_all, Us_all, nxt, rce, rco, n, off);
        float* tmp = cur; cur = nxt; nxt = tmp;
    }

    // 8) out = x @ Lk1_w^T + Lk1_b   (8192 x 512, K=1024)
    gemm_nt<<<dim3(4, 64), 256, 0, stream>>>(cur, Lk1_w, Lk1_b, out, 8192, 512, 1024);
}

// Round 2
// 2031.161 us; speedup vs baseline: 1.8143x; 1.8143x over previous
//
#include <hip/hip_runtime.h>
#include <math.h>
#include <string.h>

#define CK 1024
#define BATCH 8
#define MM_IC 16

struct F16x8 { float m[16][8]; };

// ============================ host-side filter construction ============================
// Port of _legendre_filters(8) in double precision. Deterministic, ~microseconds, pure CPU.

static void compose_poly(const double* a, int deg, double alpha, double beta, double* out16)
{
    double r[20]; for (int i = 0; i < 20; ++i) r[i] = 0.0;
    int rd = -1;
    for (int j = deg; j >= 0; --j) {
        double nr[20]; for (int i = 0; i < 20; ++i) nr[i] = 0.0;
        for (int i = 0; i <= rd; ++i) { nr[i] += beta * r[i]; nr[i + 1] += alpha * r[i]; }
        nr[0] += a[j];
        rd = (rd < 0) ? 0 : (rd + 1);
        for (int i = 0; i < 20; ++i) r[i] = nr[i];
    }
    for (int i = 0; i < 16; ++i) out16[i] = r[i];
}

static double inner_prod(const double* a, int la, const double* b, int lb, int half)
{
    double prod[40]; for (int i = 0; i < 40; ++i) prod[i] = 0.0;
    for (int i = 0; i < la; ++i)
        for (int j = 0; j < lb; ++j) prod[i + j] += a[i] * b[j];
    int lp = la + lb - 1;
    double s = 0.0;
    for (int r = 0; r < lp; ++r) {
        double p = prod[r];
        if (fabs(p) < 1e-8) p = 0.0;
        double w = pow(0.5, (double)(r + 1));
        if (!half) w = 1.0 - w;
        s += p / ((double)(r + 1)) * w;
    }
    return s;
}

static double polyval8(const double* c, double x)
{
    double r = 0.0;
    for (int i = 7; i >= 0; --i) r = r * x + c[i];
    return r;
}

static void host_filters(F16x8* ecs, F16x8* ecd, F16x8* rce, F16x8* rco)
{
    static const double Lg[8][8] = {
        {1, 0, 0, 0, 0, 0, 0, 0},
        {0, 1, 0, 0, 0, 0, 0, 0},
        {-0.5, 0, 1.5, 0, 0, 0, 0, 0},
        {0, -1.5, 0, 2.5, 0, 0, 0, 0},
        {0.375, 0, -3.75, 0, 4.375, 0, 0, 0},
        {0, 1.875, 0, -8.75, 0, 7.875, 0, 0},
        {-0.3125, 0, 6.5625, 0, -19.6875, 0, 14.4375, 0},
        {0, -2.1875, 0, 19.6875, 0, -43.3125, 0, 26.8125}
    };
    double phi[8][16], phi2[8][16], psi1[8][16], psi2[8][16];
    for (int i = 0; i < 8; ++i)
        for (int j = 0; j < 16; ++j) { phi[i][j] = 0; phi2[i][j] = 0; psi1[i][j] = 0; psi2[i][j] = 0; }

    for (int ki = 0; ki < 8; ++ki) {
        double c1[16], c2[16];
        compose_poly(Lg[ki], ki, 2.0, -1.0, c1);
        compose_poly(Lg[ki], ki, 4.0, -1.0, c2);
        double s = sqrt(2.0 * ki + 1.0);
        for (int j = 0; j <= ki; ++j) {
            phi[ki][j]  = s * c1[j];
            phi2[ki][j] = 1.4142135623730951 * s * c2[j];
        }
    }

    for (int ki = 0; ki < 8; ++ki) {
        for (int j = 0; j < 8; ++j) psi1[ki][j] = phi2[ki][j];
        for (int i = 0; i < 8; ++i) {
            double p = inner_prod(phi2[ki], ki + 1, phi[i], i + 1, 1);
            for (int j = 0; j < 8; ++j) { psi1[ki][j] -= p * phi[i][j]; psi2[ki][j] -= p * phi[i][j]; }
        }
        for (int j = 0; j < ki; ++j) {
            double p = inner_prod(phi2[ki], ki + 1, psi1[j], 8, 1);
            for (int q = 0; q < 8; ++q) { psi1[ki][q] -= p * psi1[j][q]; psi2[ki][q] -= p * psi2[j][q]; }
        }
        double n1 = inner_prod(psi1[ki], 8, psi1[ki], 8, 1);
        double n2 = inner_prod(psi2[ki], 8, psi2[ki], 8, 0);
        double nrm = sqrt(n1 + n2);
        for (int q = 0; q < 8; ++q) {
            psi1[ki][q] /= nrm; psi2[ki][q] /= nrm;
            if (fabs(psi1[ki][q]) < 1e-8) psi1[ki][q] = 0.0;
            if (fabs(psi2[ki][q]) < 1e-8) psi2[ki][q] = 0.0;
        }
    }

    static const double gx[8] = {
        -0.96028985649753623168, -0.79666647741362673959, -0.52553240991632898582, -0.18343464249564980494,
         0.18343464249564980494,  0.52553240991632898582,  0.79666647741362673959,  0.96028985649753623168 };
    static const double gw[8] = {
         0.10122853629037625915,  0.22238103445337447054,  0.31370664587788728734,  0.36268378337836198297,
         0.36268378337836198297,  0.31370664587788728734,  0.22238103445337447054,  0.10122853629037625915 };

    double H0[8][8], H1[8][8], G0[8][8], G1[8][8];
    const double s2 = 0.70710678118654752440;
    for (int ki = 0; ki < 8; ++ki) {
        for (int kpi = 0; kpi < 8; ++kpi) {
            double h0 = 0, h1 = 0, g0 = 0, g1 = 0;
            for (int mq = 0; mq < 8; ++mq) {
                double xm = (gx[mq] + 1.0) * 0.5;
                double wm = gw[mq] * 0.5;
                double pk = polyval8(phi[kpi], xm);
                h0 += wm * polyval8(phi[ki],  xm * 0.5) * pk;
                g0 += wm * polyval8(psi1[ki], xm * 0.5) * pk;
                h1 += wm * polyval8(phi[ki],  (xm + 1.0) * 0.5) * pk;
                g1 += wm * polyval8(psi2[ki], (xm + 1.0) * 0.5) * pk;
            }
            h0 *= s2; h1 *= s2; g0 *= s2; g1 *= s2;
            H0[ki][kpi] = (fabs(h0) < 1e-8) ? 0.0 : h0;
            H1[ki][kpi] = (fabs(h1) < 1e-8) ? 0.0 : h1;
            G0[ki][kpi] = (fabs(g0) < 1e-8) ? 0.0 : g0;
            G1[ki][kpi] = (fabs(g1) < 1e-8) ? 0.0 : g1;
        }
    }

    for (int r = 0; r < 8; ++r) {
        for (int c = 0; c < 8; ++c) {
            ecs->m[r][c]     = (float)H0[c][r];
            ecs->m[r + 8][c] = (float)H1[c][r];
            ecd->m[r][c]     = (float)G0[c][r];
            ecd->m[r + 8][c] = (float)G1[c][r];
            rce->m[r][c]     = (float)H0[r][c];
            rce->m[r + 8][c] = (float)G0[r][c];
            rco->m[r][c]     = (float)H1[r][c];
            rco->m[r + 8][c] = (float)G1[r][c];
        }
    }
}

// ============================ device kernels ============================

__global__ __launch_bounds__(256) void gemm_nt(
    const float* __restrict__ A, const float* __restrict__ B,
    const float* __restrict__ bias, float* __restrict__ C,
    int M, int N, int K)
{
    __shared__ __align__(16) float As[8][128];
    __shared__ __align__(16) float Bs[8][128];
    const int tid = threadIdx.x;
    const int bm = blockIdx.y * 128, bn = blockIdx.x * 128;
    const int lr = tid >> 1, lk = (tid & 1) * 4;
    const int tm = (tid >> 4) * 8, tn = (tid & 15) * 8;
    const float* Ap = A + (size_t)(bm + lr) * K + lk;
    const float* Bp = B + (size_t)(bn + lr) * K + lk;
    float acc[8][8];
#pragma unroll
    for (int i = 0; i < 8; ++i)
#pragma unroll
        for (int j = 0; j < 8; ++j) acc[i][j] = 0.f;

    for (int k0 = 0; k0 < K; k0 += 8) {
        float4 a4 = *(const float4*)(Ap + k0);
        float4 b4 = *(const float4*)(Bp + k0);
        __syncthreads();
        As[lk + 0][lr] = a4.x; As[lk + 1][lr] = a4.y; As[lk + 2][lr] = a4.z; As[lk + 3][lr] = a4.w;
        Bs[lk + 0][lr] = b4.x; Bs[lk + 1][lr] = b4.y; Bs[lk + 2][lr] = b4.z; Bs[lk + 3][lr] = b4.w;
        __syncthreads();
#pragma unroll
        for (int kk = 0; kk < 8; ++kk) {
            alignas(16) float ar[8], br[8];
            *(float4*)&ar[0] = *(const float4*)&As[kk][tm];
            *(float4*)&ar[4] = *(const float4*)&As[kk][tm + 4];
            *(float4*)&br[0] = *(const float4*)&Bs[kk][tn];
            *(float4*)&br[4] = *(const float4*)&Bs[kk][tn + 4];
#pragma unroll
            for (int i = 0; i < 8; ++i)
#pragma unroll
                for (int j = 0; j < 8; ++j) acc[i][j] = fmaf(ar[i], br[j], acc[i][j]);
        }
    }
    float bb[8];
#pragma unroll
    for (int j = 0; j < 8; ++j) bb[j] = bias[bn + tn + j];
#pragma unroll
    for (int i = 0; i < 8; ++i) {
        alignas(16) float cv[8];
#pragma unroll
        for (int j = 0; j < 8; ++j) cv[j] = acc[i][j] + bb[j];
        size_t off = (size_t)(bm + tm + i) * N + bn + tn;
        *(float4*)&C[off]     = *(float4*)&cv[0];
        *(float4*)&C[off + 4] = *(float4*)&cv[4];
    }
}

__global__ __launch_bounds__(256) void decomp_k(
    const float* __restrict__ xin, float* __restrict__ d_all, float* __restrict__ s_all,
    F16x8 ecd, F16x8 ecs, int Nh, int out_off, int in_bstride, int in_off)
{
    int idx = blockIdx.x * 256 + threadIdx.x;
    int total = BATCH * Nh * 128;
    if (idx >= total) return;
    int ch = idx & 127;
    int t  = (idx >> 7) % Nh;
    int b  = idx / (128 * Nh);
    const float* x0 = xin + ((size_t)b * in_bstride + in_off + 2 * t) * CK + ch * 8;
    alignas(16) float xa[16];
    *(float4*)&xa[0]  = *(const float4*)(x0);
    *(float4*)&xa[4]  = *(const float4*)(x0 + 4);
    *(float4*)&xa[8]  = *(const float4*)(x0 + CK);
    *(float4*)&xa[12] = *(const float4*)(x0 + CK + 4);
    alignas(16) float dd[8], ss[8];
#pragma unroll
    for (int q = 0; q < 8; ++q) { dd[q] = 0.f; ss[q] = 0.f; }
#pragma unroll
    for (int j = 0; j < 16; ++j) {
        float v = xa[j];
#pragma unroll
        for (int q = 0; q < 8; ++q) {
            dd[q] = fmaf(v, ecd.m[j][q], dd[q]);
            ss[q] = fmaf(v, ecs.m[j][q], ss[q]);
        }
    }
    size_t ob = ((size_t)b * 1023 + out_off + t) * CK + ch * 8;
    *(float4*)&d_all[ob]     = *(float4*)&dd[0];
    *(float4*)&d_all[ob + 4] = *(float4*)&dd[4];
    *(float4*)&s_all[ob]     = *(float4*)&ss[0];
    *(float4*)&s_all[ob + 4] = *(float4*)&ss[4];
}

template<int LN>
__global__ __launch_bounds__(256) void dft_k(
    const float* __restrict__ d_all, const float* __restrict__ s_all,
    float* __restrict__ Xd, float* __restrict__ Xs, int lev0)
{
    const int lev = lev0 + (int)blockIdx.z / 2;
    const int src = (int)blockIdx.z & 1;
    const int Nh  = 512 >> lev;
    const int off = 1024 - (1024 >> lev);
    const int i   = blockIdx.x * 256 + threadIdx.x;
    const int b   = blockIdx.y;
    const float* inp = (src == 0 ? d_all : s_all) + ((size_t)b * 1023 + off) * CK + i;
    float* Xout = (src == 0 ? Xd : Xs);
    float accr[LN], acci[LN];
#pragma unroll
    for (int m = 0; m < LN; ++m) { accr[m] = 0.f; acci[m] = 0.f; }
    __shared__ float2 tw[128][LN];
    for (int t0 = 0; t0 < Nh; t0 += 128) {
        int tc = Nh - t0; if (tc > 128) tc = 128;
        __syncthreads();
        for (int e = threadIdx.x; e < tc * LN; e += 256) {
            int tt = e / LN, m = e - tt * LN;
            int r = (int)(((long long)(t0 + tt) * m) % Nh);
            float ang = -6.283185307179586f * (float)r / (float)Nh;
            float sv, cv;
            sincosf(ang, &sv, &cv);
            tw[tt][m] = make_float2(cv, sv);
        }
        __syncthreads();
        for (int tt = 0; tt < tc; ++tt) {
            float v = inp[(size_t)(t0 + tt) * CK];
#pragma unroll
            for (int m = 0; m < LN; ++m) {
                float2 w = tw[tt][m];
                accr[m] = fmaf(v, w.x, accr[m]);
                acci[m] = fmaf(v, w.y, acci[m]);
            }
        }
    }
#pragma unroll
    for (int m = 0; m < LN; ++m) {
        size_t row = (size_t)((lev * 8 + b) * 16 + m);
        *(float2*)(Xout + row * 2048 + 2 * i) = make_float2(accr[m], acci[m]);
    }
}

// mode mixing v2: split-K over i (x8), all 8 batches per thread, X staged in LDS,
// atomicAdd epilogue into zero-initialized Uhd/Uhs.
// Grid: 1280 blocks = 16 o-tiles x 8 i-splits x 10 levels, swizzled so the 10
// level-blocks sharing one (o-tile,i-split) weight stream land on one XCD.
__global__ __launch_bounds__(256) void modemix_k(
    const float* __restrict__ wAre, const float* __restrict__ wAim,
    const float* __restrict__ wBre, const float* __restrict__ wBim,
    const float* __restrict__ wCre, const float* __restrict__ wCim,
    const float* __restrict__ Xd, const float* __restrict__ Xs,
    float* __restrict__ Uhd, float* __restrict__ Uhs)
{
    const int bid  = (int)blockIdx.x;
    const int xcd  = bid & 7, slot = bid >> 3;        // slot 0..159
    const int g    = xcd * 16 + slot / 10;            // 0..127 (ot,isp) group
    const int lev  = slot - (slot / 10) * 10;         // 0..9
    const int ot   = g & 15, isp = g >> 4;
    const int Nh   = 512 >> lev;
    const int ln   = min(16, (Nh >> 1) + 1);
    const int lane = (int)threadIdx.x & 63;
    const int mg   = (int)threadIdx.x >> 6;
    const int m0   = mg * 4;
    const int o    = ot * 64 + lane;
    const int i0   = isp * 128;
    const int nvalid = ln - m0;                       // >0 means this wave computes

    __shared__ float xsh[MM_IC][516];                 // [ii][(m*8+b)*4 + {xdre,xdim,xsre,xsim}]

    float acc[4][8][4];
#pragma unroll
    for (int mi = 0; mi < 4; ++mi)
#pragma unroll
        for (int b = 0; b < 8; ++b)
#pragma unroll
            for (int q = 0; q < 4; ++q) acc[mi][b][q] = 0.f;

    for (int c = 0; c < 128 / MM_IC; ++c) {
        const int ib = i0 + c * MM_IC;
        __syncthreads();
        // stage X for this i-chunk: all 16 modes x 8 batches (rows m>=ln hold unused junk)
#pragma unroll 2
        for (int e = (int)threadIdx.x; e < 128 * MM_IC; e += 256) {
            int ii = e & (MM_IC - 1);
            int mb = e >> 4;                          // m*8+b
            int m = mb >> 3, b = mb & 7;
            size_t row = (size_t)((lev * 8 + b) * 16 + m);
            float2 vd = *(const float2*)(Xd + row * 2048 + 2 * (ib + ii));
            float2 vs = *(const float2*)(Xs + row * 2048 + 2 * (ib + ii));
            *(float4*)&xsh[ii][mb * 4] = make_float4(vd.x, vd.y, vs.x, vs.y);
        }
        __syncthreads();
        if (nvalid > 0) {
            for (int ii = 0; ii < MM_IC; ++ii) {
                size_t wo = ((size_t)(ib + ii) * 1024 + o) * 16 + m0;
                float4 war = *(const float4*)(wAre + wo);
                float4 wai = *(const float4*)(wAim + wo);
                float4 wbr = *(const float4*)(wBre + wo);
                float4 wbi = *(const float4*)(wBim + wo);
                float4 wcr = *(const float4*)(wCre + wo);
                float4 wci = *(const float4*)(wCim + wo);
                const float warr[4] = {war.x, war.y, war.z, war.w};
                const float wair[4] = {wai.x, wai.y, wai.z, wai.w};
                const float wbrr[4] = {wbr.x, wbr.y, wbr.z, wbr.w};
                const float wbir[4] = {wbi.x, wbi.y, wbi.z, wbi.w};
                const float wcrr[4] = {wcr.x, wcr.y, wcr.z, wcr.w};
                const float wcir[4] = {wci.x, wci.y, wci.z, wci.w};
#pragma unroll
                for (int mi = 0; mi < 4; ++mi) {
                    if (mi < nvalid) {                // wave-uniform (ln, m0 uniform)
                        const float ar_ = warr[mi], ai_ = wair[mi];
                        const float br_ = wbrr[mi], bi_ = wbir[mi];
                        const float cr_ = wcrr[mi], ci_ = wcir[mi];
#pragma unroll
                        for (int b = 0; b < 8; ++b) {
                            float4 x4 = *(const float4*)&xsh[ii][((m0 + mi) * 8 + b) * 4];
                            acc[mi][b][0] += x4.x * ar_ - x4.y * ai_ + x4.z * br_ - x4.w * bi_;
                            acc[mi][b][1] += x4.x * ai_ + x4.y * ar_ + x4.z * bi_ + x4.w * br_;
                            acc[mi][b][2] += x4.x * cr_ - x4.y * ci_;
                            acc[mi][b][3] += x4.x * ci_ + x4.y * cr_;
                        }
                    }
                }
            }
        }
    }

#pragma unroll
    for (int mi = 0; mi < 4; ++mi) {
        if (mi < nvalid) {
#pragma unroll
            for (int b = 0; b < 8; ++b) {
                size_t row = (size_t)((lev * 8 + b) * 16 + m0 + mi);
                atomicAdd(&Uhd[row * 2048 + 2 * o],     acc[mi][b][0]);
                atomicAdd(&Uhd[row * 2048 + 2 * o + 1], acc[mi][b][1]);
                atomicAdd(&Uhs[row * 2048 + 2 * o],     acc[mi][b][2]);
                atomicAdd(&Uhs[row * 2048 + 2 * o + 1], acc[mi][b][3]);
            }
        }
    }
}

template<int LN>
__global__ __launch_bounds__(256) void idft_k(
    const float* __restrict__ Uhd, const float* __restrict__ Uhs,
    float* __restrict__ Ud_all, float* __restrict__ Us_all, int lev0)
{
    const int lev = lev0 + (int)blockIdx.z / 8;
    const int chunk = (int)blockIdx.z & 7;
    const int Nh  = 512 >> lev;
    const int off = 1024 - (1024 >> lev);
    const int nch = (Nh + 7) >> 3;
    const int t0 = chunk * nch;
    if (t0 >= Nh) return;
    int t1 = t0 + nch; if (t1 > Nh) t1 = Nh;
    const int o = blockIdx.x * 256 + threadIdx.x;
    const int b = blockIdx.y;
    const float invN = 1.0f / (float)Nh;

    float udr[LN], udi[LN], usr[LN], usi[LN], rc[LN], rs[LN], stc[LN], sts[LN];
#pragma unroll
    for (int m = 0; m < LN; ++m) {
        size_t row = (size_t)((lev * 8 + b) * 16 + m);
        float2 vd = *(const float2*)(Uhd + row * 2048 + 2 * o);
        float2 vs = *(const float2*)(Uhs + row * 2048 + 2 * o);
        bool nyq = (2 * m == Nh);
        float cm = (m == 0 || nyq) ? 1.f : 2.f;
        float sc = cm * invN;
        udr[m] = vd.x * sc; usr[m] = vs.x * sc;
        udi[m] = (m == 0 || nyq) ? 0.f : vd.y * sc;
        usi[m] = (m == 0 || nyq) ? 0.f : vs.y * sc;
        int r = (int)(((long long)m * t0) % Nh);
        float a0 = 6.283185307179586f * (float)r / (float)Nh;
        sincosf(a0, &rs[m], &rc[m]);
        float a1 = 6.283185307179586f * (float)m / (float)Nh;
        sincosf(a1, &sts[m], &stc[m]);
    }
    for (int t = t0; t < t1; ++t) {
        float od = 0.f, os = 0.f;
#pragma unroll
        for (int m = 0; m < LN; ++m) {
            od += udr[m] * rc[m] - udi[m] * rs[m];
            os += usr[m] * rc[m] - usi[m] * rs[m];
            float nc = rc[m] * stc[m] - rs[m] * sts[m];
            float ns = rs[m] * stc[m] + rc[m] * sts[m];
            rc[m] = nc; rs[m] = ns;
        }
        size_t ob = ((size_t)b * 1023 + off + t) * CK + o;
        Ud_all[ob] = od; Us_all[ob] = os;
    }
}

__global__ __launch_bounds__(256) void t0_k(
    const float* __restrict__ s_all, const float* __restrict__ T0_w,
    const float* __restrict__ T0_b, float* __restrict__ xout)
{
    int idx = blockIdx.x * 256 + threadIdx.x;
    int o = idx & 1023, b = idx >> 10;
    int ki = o & 7, ch = o >> 3;
    const float* src = s_all + ((size_t)b * 1023 + 1022) * CK + ch * 8;
    float acc = T0_b[ki];
#pragma unroll
    for (int kj = 0; kj < 8; ++kj) acc += src[kj] * T0_w[ki * 8 + kj];
    xout[(size_t)b * 1024 + o] = acc;
}

__global__ __launch_bounds__(256) void recon_k(
    const float* __restrict__ xin, const float* __restrict__ Ud_all, const float* __restrict__ Us_all,
    float* __restrict__ xout, F16x8 rce, F16x8 rco, int n, int lev_off)
{
    int idx = blockIdx.x * 256 + threadIdx.x;
    int total = BATCH * n * 128;
    if (idx >= total) return;
    int ch = idx & 127;
    int t  = (idx >> 7) % n;
    int b  = idx / (128 * n);
    size_t ib = ((size_t)b * n + t) * CK + ch * 8;
    size_t ub = ((size_t)b * 1023 + lev_off + t) * CK + ch * 8;
    alignas(16) float xc[16];
    float4 xv0 = *(const float4*)(xin + ib);
    float4 xv1 = *(const float4*)(xin + ib + 4);
    float4 us0 = *(const float4*)(Us_all + ub);
    float4 us1 = *(const float4*)(Us_all + ub + 4);
    xc[0] = xv0.x + us0.x; xc[1] = xv0.y + us0.y; xc[2] = xv0.z + us0.z; xc[3] = xv0.w + us0.w;
    xc[4] = xv1.x + us1.x; xc[5] = xv1.y + us1.y; xc[6] = xv1.z + us1.z; xc[7] = xv1.w + us1.w;
    float4 ud0 = *(const float4*)(Ud_all + ub);
    float4 ud1 = *(const float4*)(Ud_all + ub + 4);
    xc[8] = ud0.x; xc[9] = ud0.y; xc[10] = ud0.z; xc[11] = ud0.w;
    xc[12] = ud1.x; xc[13] = ud1.y; xc[14] = ud1.z; xc[15] = ud1.w;
    alignas(16) float ev[8], ov[8];
#pragma unroll
    for (int q = 0; q < 8; ++q) { ev[q] = 0.f; ov[q] = 0.f; }
#pragma unroll
    for (int j = 0; j < 16; ++j) {
        float v = xc[j];
#pragma unroll
        for (int q = 0; q < 8; ++q) {
            ev[q] = fmaf(v, rce.m[j][q], ev[q]);
            ov[q] = fmaf(v, rco.m[j][q], ov[q]);
        }
    }
    size_t ob = ((size_t)b * 2 * n + 2 * t) * CK + ch * 8;
    *(float4*)&xout[ob]          = *(float4*)&ev[0];
    *(float4*)&xout[ob + 4]      = *(float4*)&ev[4];
    *(float4*)&xout[ob + CK]     = *(float4*)&ov[0];
    *(float4*)&xout[ob + CK + 4] = *(float4*)&ov[4];
}

// ============================ launch ============================

extern "C" void kernel_launch(void* const* d_in, const int* in_sizes, int n_in,
                              void* d_out, int out_size, void* d_ws, size_t ws_size,
                              hipStream_t stream)
{
    (void)in_sizes; (void)n_in; (void)out_size; (void)ws_size;
    const float* values = (const float*)d_in[2];
    const float* Lk0_w  = (const float*)d_in[3];
    const float* Lk0_b  = (const float*)d_in[4];
    const float* Lk1_w  = (const float*)d_in[5];
    const float* Lk1_b  = (const float*)d_in[6];
    const float* T0_w   = (const float*)d_in[7];
    const float* T0_b   = (const float*)d_in[8];
    const float* wAre   = (const float*)d_in[9];
    const float* wAim   = (const float*)d_in[10];
    const float* wBre   = (const float*)d_in[11];
    const float* wBim   = (const float*)d_in[12];
    const float* wCre   = (const float*)d_in[13];
    const float* wCim   = (const float*)d_in[14];
    float* out = (float*)d_out;
    float* ws  = (float*)d_ws;

    float* V0     = ws;                      // 8388608
    float* xrB    = V0 + 8388608;            // 4194304
    float* d_all  = xrB + 4194304;           // 8380416
    float* s_all  = d_all + 8380416;         // 8380416
    float* Ud_all = s_all + 8380416;         // 8380416
    float* Us_all = Ud_all + 8380416;        // 8380416
    float* Xd     = Us_all + 8380416;        // 2621440
    float* Xs     = Xd + 2621440;            // 2621440
    float* Uhd    = d_all;                   // overlay: d_all dead after DFT phase
    float* Uhs    = d_all + 2621440;

    F16x8 ecs, ecd, rce, rco;
    host_filters(&ecs, &ecd, &rce, &rco);

    // 1) V0 = values @ Lk0_w^T + Lk0_b
    gemm_nt<<<dim3(8, 64), 256, 0, stream>>>(values, Lk0_w, Lk0_b, V0, 8192, 1024, 512);

    // 2) decomposition cascade
    for (int lev = 0; lev < 10; ++lev) {
        int Nh = 512 >> lev;
        int out_off = 1024 - (1024 >> lev);
        const float* xin; int in_bs, in_off;
        if (lev == 0) { xin = V0; in_bs = 1024; in_off = 0; }
        else { xin = s_all; in_bs = 1023; in_off = 1024 - (1024 >> (lev - 1)); }
        int blocks = (BATCH * Nh * 128 + 255) / 256;
        decomp_k<<<blocks, 256, 0, stream>>>(xin, d_all, s_all, ecd, ecs, Nh, out_off, in_bs, in_off);
    }

    // 3) forward truncated DFTs
    dft_k<16><<<dim3(4, 8, 10), 256, 0, stream>>>(d_all, s_all, Xd, Xs, 0);
    dft_k<9> <<<dim3(4, 8, 2), 256, 0, stream>>>(d_all, s_all, Xd, Xs, 5);
    dft_k<5> <<<dim3(4, 8, 2), 256, 0, stream>>>(d_all, s_all, Xd, Xs, 6);
    dft_k<3> <<<dim3(4, 8, 2), 256, 0, stream>>>(d_all, s_all, Xd, Xs, 7);
    dft_k<2> <<<dim3(4, 8, 2), 256, 0, stream>>>(d_all, s_all, Xd, Xs, 8);
    dft_k<1> <<<dim3(4, 8, 2), 256, 0, stream>>>(d_all, s_all, Xd, Xs, 9);

    // 4) T0 map
    t0_k<<<32, 256, 0, stream>>>(s_all, T0_w, T0_b, V0);

    // 5) zero Uhat accumulators (d_all dead now), then mode mixing with split-K atomics
    hipMemsetAsync(Uhd, 0, (size_t)2 * 2621440 * sizeof(float), stream);
    modemix_k<<<1280, 256, 0, stream>>>(wAre, wAim, wBre, wBim, wCre, wCim, Xd, Xs, Uhd, Uhs);

    // 6) inverse truncated DFTs
    idft_k<16><<<dim3(4, 8, 40), 256, 0, stream>>>(Uhd, Uhs, Ud_all, Us_all, 0);
    idft_k<9> <<<dim3(4, 8, 8), 256, 0, stream>>>(Uhd, Uhs, Ud_all, Us_all, 5);
    idft_k<5> <<<dim3(4, 8, 8), 256, 0, stream>>>(Uhd, Uhs, Ud_all, Us_all, 6);
    idft_k<3> <<<dim3(4, 8, 8), 256, 0, stream>>>(Uhd, Uhs, Ud_all, Us_all, 7);
    idft_k<2> <<<dim3(4, 8, 8), 256, 0, stream>>>(Uhd, Uhs, Ud_all, Us_all, 8);
    idft_k<1> <<<dim3(4, 8, 8), 256, 0, stream>>>(Uhd, Uhs, Ud_all, Us_all, 9);

    // 7) reconstruction cascade
    float* cur = V0; float* nxt = xrB;
    for (int lv = 9; lv >= 0; --lv) {
        int n = 512 >> lv;
        int off = 1024 - (1024 >> lv);
        int blocks = (BATCH * n * 128 + 255) / 256;
        recon_k<<<blocks, 256, 0, stream>>>(cur, Ud_all, Us_all, nxt, rce, rco, n, off);
        float* tmp = cur; cur = nxt; nxt = tmp;
    }

    // 8) out = x @ Lk1_w^T + Lk1_b
    gemm_nt<<<dim3(4, 64), 256, 0, stream>>>(cur, Lk1_w, Lk1_b, out, 8192, 512, 1024);
}